// Round 7
// baseline (455.453 us; speedup 1.0000x reference)
//
#include <hip/hip_runtime.h>

typedef _Float16 f16;
typedef f16 f16x8 __attribute__((ext_vector_type(8)));
typedef float f32x4 __attribute__((ext_vector_type(4)));
typedef unsigned short u16;

#define IN_CH  256
#define HID    256
#define OUT_CH 128
#define LN_EPS 1e-5f
#define NSLOT  32   // sig partial slots
#define NR     8    // node ranges (histogram privatization by range, LDS-sized)
#define NC     32   // edge chunks (per-chunk histogram copies -> atomic-free fill)
#define RS     6272 // max range size: ceil(50000/8)=6250, padded

// ---------------- hist: packed LDS histogram (deg<<16 | cnt), no global atomics ----------------
// + weight-prep blocks (prepw traffic is tiny; 25KB LDS still allows 6 blocks/CU)

__global__ __launch_bounds__(256) void k_hist(const int* __restrict__ ei, int nE, int nN,
                                              int* __restrict__ hist_c,   // [NC][nN] packed
                                              const float* __restrict__ sigw, const float* __restrict__ c1w,
                                              const float* __restrict__ c2w,
                                              f16* __restrict__ Wt1, f16* __restrict__ Wt2) {
    __shared__ int h[RS];
    int bid = blockIdx.x;
    int nT = nE + nN;
    if (bid < NR * NC) {
        int r = bid & (NR - 1), c = bid >> 3;
        int rsz = (nN + NR - 1) / NR;
        int r0 = r * rsz;
        int sz = nN - r0; if (sz > rsz) sz = rsz;
        for (int i = threadIdx.x; i < sz; i += 256) h[i] = 0;
        __syncthreads();
        int chunk = (nT + NC - 1) / NC;
        int e0 = c * chunk, e1 = e0 + chunk; if (e1 > nT) e1 = nT;
        for (int e = e0 + threadIdx.x; e < e1; e += 256) {
            int s, d;
            if (e < nE) { s = ei[e]; d = ei[nE + e]; } else { s = d = e - nE; }
            if ((unsigned)(s - r0) < (unsigned)sz) atomicAdd(&h[s - r0], 0x10000);  // deg (src)
            if ((unsigned)(d - r0) < (unsigned)sz) atomicAdd(&h[d - r0], 1);        // cnt (dst)
        }
        __syncthreads();
        for (int i = threadIdx.x; i < sz; i += 256)
            hist_c[(size_t)c * nN + r0 + i] = h[i];
    } else {
        int i = (bid - NR * NC) * 256 + threadIdx.x;
        if (i < 512 * 256) {
            int n = i >> 8, k = i & 255;
            float v = (n < 256) ? sigw[k * 256 + n] : c1w[k * 256 + (n - 256)];
            Wt1[(size_t)n * 256 + k] = (f16)v;
        } else {
            int j = i - 512 * 256;
            if (j < 128 * 256) {
                int n = j >> 8, k = j & 255;
                Wt2[(size_t)n * 256 + k] = (f16)c2w[k * 128 + n];
            }
        }
    }
}

// reduce NC packed chunk copies -> totals, dinv, CSR slice alloc (wave-prefix + 1 atomic/wave),
// per-chunk base offsets (makes fill atomic-free)
__global__ __launch_bounds__(256) void k_alloc(const int* __restrict__ hist_c,
                                               int* __restrict__ rowstart,
                                               int* __restrict__ chunkbase,
                                               int* __restrict__ cnt_tot,
                                               float* __restrict__ dinv,
                                               int* __restrict__ ctr, int nN) {
    int i = blockIdx.x * 256 + threadIdx.x;
    int lane = threadIdx.x & 63;
    int cc[NC];
    int cnt = 0, dg = 0;
    if (i < nN) {
        #pragma unroll
        for (int c = 0; c < NC; c++) {
            unsigned v = (unsigned)hist_c[(size_t)c * nN + i];
            cc[c] = (int)(v & 0xffffu);
            cnt += cc[c];
            dg += (int)(v >> 16);
        }
    }
    int p = cnt;
    #pragma unroll
    for (int off = 1; off < 64; off <<= 1) {
        int v = __shfl_up(p, off, 64);
        if (lane >= off) p += v;
    }
    int tot = __shfl(p, 63, 64);
    int base = 0;
    if (lane == 0) base = atomicAdd(ctr, tot);
    base = __shfl(base, 0, 64);
    if (i < nN) {
        int nb = base + p - cnt;
        rowstart[i] = nb;
        cnt_tot[i] = cnt;
        dinv[i] = rsqrtf((float)dg);  // deg >= 1 (self loop)
        int run = nb;
        #pragma unroll
        for (int c = 0; c < NC; c++) { chunkbase[(size_t)c * nN + i] = run; run += cc[c]; }
    }
}

// fill (counting sort, LDS running cursor = chunkbase staged; no off_ array)
// + cast blocks: xh = (f16)(x * dinv[row])  (scale folded into the cast; 25KB LDS -> 6 blk/CU)
__global__ __launch_bounds__(256) void k_fillcast(const int* __restrict__ ei, int nE, int nN,
                                                  const int* __restrict__ chunkbase,
                                                  u16* __restrict__ src_sorted,
                                                  const float* __restrict__ x, f16* __restrict__ xh,
                                                  const float* __restrict__ dinv, int nCast) {
    __shared__ int bs[RS];
    int bid = blockIdx.x;
    int nT = nE + nN;
    if (bid < NR * NC) {
        int r = bid & (NR - 1), c = bid >> 3;
        int rsz = (nN + NR - 1) / NR;
        int r0 = r * rsz;
        int sz = nN - r0; if (sz > rsz) sz = rsz;
        for (int i = threadIdx.x; i < sz; i += 256)
            bs[i] = chunkbase[(size_t)c * nN + r0 + i];
        __syncthreads();
        int chunk = (nT + NC - 1) / NC;
        int e0 = c * chunk, e1 = e0 + chunk; if (e1 > nT) e1 = nT;
        for (int e = e0 + threadIdx.x; e < e1; e += 256) {
            int s, d;
            if (e < nE) { s = ei[e]; d = ei[nE + e]; } else { s = d = e - nE; }
            int l = d - r0;
            if ((unsigned)l < (unsigned)sz) {
                int pos = atomicAdd(&bs[l], 1);
                src_sorted[pos] = (u16)s;
            }
        }
    } else {
        int cb = bid - NR * NC;
        if (cb >= nCast) return;
        int i = cb * 2048 + threadIdx.x * 8;
        if (i >= nN * 256) return;
        float dn = dinv[i >> 8];
        float4 a = *(const float4*)(x + i);
        float4 b = *(const float4*)(x + i + 4);
        f16x8 o = { (f16)(a.x * dn), (f16)(a.y * dn), (f16)(a.z * dn), (f16)(a.w * dn),
                    (f16)(b.x * dn), (f16)(b.y * dn), (f16)(b.z * dn), (f16)(b.w * dn) };
        *(f16x8*)(xh + i) = o;
    }
}

// ---------------- AX = dinv_d * sum(xh'[src])  (xh pre-scaled by dinv_src) ----------------
// wave per node; half-wave per edge; 16B loads; x2 unroll = 4 gathers in flight

__global__ __launch_bounds__(256) void k_aggX(const f16* __restrict__ xh,
                                              const int* __restrict__ rowstart,
                                              const int* __restrict__ counts,
                                              const u16* __restrict__ srcs,
                                              const float* __restrict__ dinv,
                                              f16* __restrict__ AX, int nN) {
    int wv = threadIdx.x >> 6;
    int lane = threadIdx.x & 63;
    int node = blockIdx.x * 4 + wv;
    if (node >= nN) return;
    int h = lane >> 5, sub = lane & 31;
    int beg = rowstart[node];
    int end = beg + counts[node];
    float acc0[8] = {}, acc1[8] = {};
    for (int e0 = beg; e0 < end; e0 += 4) {
        int ea = e0 + h, eb = e0 + 2 + h;
        bool oka = ea < end, okb = eb < end;
        int ia = oka ? ea : beg;
        int ib = okb ? eb : beg;
        int sa = srcs[ia], sb = srcs[ib];
        float na = oka ? 1.f : 0.f;
        float nb = okb ? 1.f : 0.f;
        f16x8 va = *(const f16x8*)(xh + (size_t)sa * 256 + sub * 8);
        f16x8 vb = *(const f16x8*)(xh + (size_t)sb * 256 + sub * 8);
        #pragma unroll
        for (int j = 0; j < 8; j++) {
            acc0[j] = fmaf(na, (float)va[j], acc0[j]);
            acc1[j] = fmaf(nb, (float)vb[j], acc1[j]);
        }
    }
    float dn = dinv[node];
    #pragma unroll
    for (int j = 0; j < 8; j++) {
        acc0[j] += acc1[j];
        acc0[j] += __shfl_xor(acc0[j], 32, 64);
    }
    if (lane < 32) {
        f16x8 o;
        #pragma unroll
        for (int j = 0; j < 8; j++) o[j] = (f16)(acc0[j] * dn);
        *(f16x8*)(AX + (size_t)node * 256 + sub * 8) = o;
    }
}

// ---------------- GEMM(sig): relu(AX @ sig_w + sigb) column-summed -> sig_part ----------------

__global__ __launch_bounds__(256) void k_gemm_sig(const f16* __restrict__ AX,
                                                  const f16* __restrict__ Wt,
                                                  const float* __restrict__ sigb,
                                                  float* __restrict__ sig_part, int M) {
    __shared__ float tile[32][257];
    int t = threadIdx.x;
    int w = t >> 6, lane = t & 63, quad = lane >> 4, l16 = lane & 15;
    int m0 = blockIdx.x * 32;
    int cb = w * 64;
    f32x4 acc[2][4] = {};
    for (int kk = 0; kk < 256; kk += 32) {
        int ka = kk + quad * 8;
        f16x8 a[2];
        #pragma unroll
        for (int ms = 0; ms < 2; ms++) {
            int row = m0 + ms * 16 + l16; if (row >= M) row = M - 1;
            a[ms] = *(const f16x8*)(AX + (size_t)row * 256 + ka);
        }
        #pragma unroll
        for (int ns = 0; ns < 4; ns++) {
            f16x8 b = *(const f16x8*)(Wt + (size_t)(cb + ns * 16 + l16) * 256 + ka);
            acc[0][ns] = __builtin_amdgcn_mfma_f32_16x16x32_f16(a[0], b, acc[0][ns], 0, 0, 0);
            acc[1][ns] = __builtin_amdgcn_mfma_f32_16x16x32_f16(a[1], b, acc[1][ns], 0, 0, 0);
        }
    }
    #pragma unroll
    for (int ms = 0; ms < 2; ms++)
        #pragma unroll
        for (int ns = 0; ns < 4; ns++)
            #pragma unroll
            for (int r = 0; r < 4; r++) {
                int mr = ms * 16 + quad * 4 + r;
                int c = cb + ns * 16 + l16;
                float v = fmaxf(acc[ms][ns][r] + sigb[c], 0.f);
                if (m0 + mr >= M) v = 0.f;
                tile[mr][c] = v;
            }
    __syncthreads();
    float s = 0.f;
    #pragma unroll 8
    for (int r = 0; r < 32; r++) s += tile[r][t];
    atomicAdd(&sig_part[(blockIdx.x & (NSLOT - 1)) * 256 + t], s);
}

// ---------------- FC: reduce slots -> s, then gamma/beta = tanh(s @ W.T + b) ----------------

__global__ __launch_bounds__(256) void k_fc(const float* __restrict__ sig_part,
                                            const float* __restrict__ f1w, const float* __restrict__ f1b,
                                            const float* __restrict__ f2w, const float* __restrict__ f2b,
                                            const float* __restrict__ f3w, const float* __restrict__ f3b,
                                            const float* __restrict__ f4w, const float* __restrict__ f4b,
                                            float* __restrict__ g1, float* __restrict__ b1,
                                            float* __restrict__ g2, float* __restrict__ b2) {
    __shared__ float ss[256];
    int t = threadIdx.x;
    float s = 0.f;
    for (int k = 0; k < NSLOT; k++) s += sig_part[k * 256 + t];
    ss[t] = s;
    __syncthreads();
    float a1 = 0.f, a2 = 0.f, a3 = 0.f, a4 = 0.f;
    const float* w1 = f1w + (size_t)t * 256;
    const float* w2 = f2w + (size_t)t * 256;
    const float* w3 = f3w + (size_t)(t & 127) * 256;
    const float* w4 = f4w + (size_t)(t & 127) * 256;
    for (int j = 0; j < 256; j++) {
        float sj = ss[j];
        a1 = fmaf(w1[j], sj, a1); a2 = fmaf(w2[j], sj, a2);
        a3 = fmaf(w3[j], sj, a3); a4 = fmaf(w4[j], sj, a4);
    }
    g1[t] = tanhf(a1 + f1b[t]);
    b1[t] = tanhf(a2 + f2b[t]);
    if (t < 128) {
        g2[t] = tanhf(a3 + f3b[t]);
        b2[t] = tanhf(a4 + f4b[t]);
    }
}

// ---------------- fused: conv1-GEMM + FiLM + relu + LN -> (LDS) -> conv2-GEMM -> HW' ----------------
// HW' rows pre-scaled by dinv[m] so agg2 needs no per-edge dinv gather

__global__ __launch_bounds__(256) void k_c1f(const f16* __restrict__ AX,
                                             const f16* __restrict__ Wt,   // conv1 rows (256x256)
                                             const f16* __restrict__ Wt2,  // conv2 rows (128x256)
                                             const float* __restrict__ g1,
                                             const float* __restrict__ b1,
                                             const float* __restrict__ c1b,
                                             const float* __restrict__ dinv,
                                             f16* __restrict__ HW, int M) {
    __shared__ float tile[32][257];
    __shared__ f16 ht[32][264];
    __shared__ float ps[8][33], ps2[8][33];
    __shared__ float mu_[32], rr_[32], sdinv[32];
    int t = threadIdx.x;
    int w = t >> 6, lane = t & 63, quad = lane >> 4, l16 = lane & 15;
    int m0 = blockIdx.x * 32;
    int cb = w * 64;
    f32x4 acc[2][4] = {};
    for (int kk = 0; kk < 256; kk += 32) {
        int ka = kk + quad * 8;
        f16x8 a[2];
        #pragma unroll
        for (int ms = 0; ms < 2; ms++) {
            int row = m0 + ms * 16 + l16; if (row >= M) row = M - 1;
            a[ms] = *(const f16x8*)(AX + (size_t)row * 256 + ka);
        }
        #pragma unroll
        for (int ns = 0; ns < 4; ns++) {
            f16x8 b = *(const f16x8*)(Wt + (size_t)(cb + ns * 16 + l16) * 256 + ka);
            acc[0][ns] = __builtin_amdgcn_mfma_f32_16x16x32_f16(a[0], b, acc[0][ns], 0, 0, 0);
            acc[1][ns] = __builtin_amdgcn_mfma_f32_16x16x32_f16(a[1], b, acc[1][ns], 0, 0, 0);
        }
    }
    #pragma unroll
    for (int ms = 0; ms < 2; ms++)
        #pragma unroll
        for (int ns = 0; ns < 4; ns++)
            #pragma unroll
            for (int r = 0; r < 4; r++) {
                int mr = ms * 16 + quad * 4 + r;
                int c = cb + ns * 16 + l16;
                tile[mr][c] = fmaxf(fmaf(g1[c], acc[ms][ns][r], b1[c] + c1b[c]), 0.f);
            }
    __syncthreads();
    {
        int r = t & 31, seg = t >> 5;
        float s = 0.f, s2 = 0.f;
        #pragma unroll 8
        for (int c = seg * 32; c < seg * 32 + 32; c++) {
            float xv = tile[r][c];
            s += xv; s2 = fmaf(xv, xv, s2);
        }
        ps[seg][r] = s; ps2[seg][r] = s2;
    }
    __syncthreads();
    if (t < 32) {
        float S = 0.f, S2 = 0.f;
        #pragma unroll
        for (int g = 0; g < 8; g++) { S += ps[g][t]; S2 += ps2[g][t]; }
        float mu = S * (1.f / 256.f);
        mu_[t] = mu;
        rr_[t] = rsqrtf(S2 * (1.f / 256.f) - mu * mu + LN_EPS);
        int m = m0 + t;
        sdinv[t] = (m < M) ? dinv[m] : 0.f;
    }
    __syncthreads();
    #pragma unroll 8
    for (int r = 0; r < 32; r++)
        ht[r][t] = (f16)((tile[r][t] - mu_[r]) * rr_[r]);
    __syncthreads();
    int cb2 = w * 32;
    f32x4 acc2[2][2] = {};
    for (int kk = 0; kk < 256; kk += 32) {
        int ka = kk + quad * 8;
        f16x8 a[2];
        #pragma unroll
        for (int ms = 0; ms < 2; ms++)
            a[ms] = *(const f16x8*)(&ht[ms * 16 + l16][ka]);
        #pragma unroll
        for (int ns = 0; ns < 2; ns++) {
            f16x8 b = *(const f16x8*)(Wt2 + (size_t)(cb2 + ns * 16 + l16) * 256 + ka);
            acc2[0][ns] = __builtin_amdgcn_mfma_f32_16x16x32_f16(a[0], b, acc2[0][ns], 0, 0, 0);
            acc2[1][ns] = __builtin_amdgcn_mfma_f32_16x16x32_f16(a[1], b, acc2[1][ns], 0, 0, 0);
        }
    }
    #pragma unroll
    for (int ms = 0; ms < 2; ms++)
        #pragma unroll
        for (int ns = 0; ns < 2; ns++)
            #pragma unroll
            for (int r = 0; r < 4; r++) {
                int mr = ms * 16 + quad * 4 + r;
                int m = m0 + mr;
                if (m < M) HW[(size_t)m * 128 + cb2 + ns * 16 + l16] = (f16)(acc2[ms][ns][r] * sdinv[mr]);
            }
}

// ---------------- agg2: out = LN(g2 * dinv_d * sum(HW'[src]) + b2 + c2b) ----------------
// wave per node; quarter-wave per edge; x2 unroll = 8 gathers in flight

__global__ __launch_bounds__(256) void k_agg2(const f16* __restrict__ HW,
                                              const int* __restrict__ rowstart,
                                              const int* __restrict__ counts,
                                              const u16* __restrict__ srcs,
                                              const float* __restrict__ dinv,
                                              const float* __restrict__ g2,
                                              const float* __restrict__ b2,
                                              const float* __restrict__ c2b,
                                              float* __restrict__ out, int nN) {
    int wv = threadIdx.x >> 6;
    int lane = threadIdx.x & 63;
    int node = blockIdx.x * 4 + wv;
    if (node >= nN) return;
    int q = lane >> 4, sub = lane & 15;
    int beg = rowstart[node];
    int end = beg + counts[node];
    float acc0[8] = {}, acc1[8] = {};
    for (int e0 = beg; e0 < end; e0 += 8) {
        int ea = e0 + q, eb = e0 + 4 + q;
        bool oka = ea < end, okb = eb < end;
        int ia = oka ? ea : beg;
        int ib = okb ? eb : beg;
        int sa = srcs[ia], sb = srcs[ib];
        float na = oka ? 1.f : 0.f;
        float nb = okb ? 1.f : 0.f;
        f16x8 va = *(const f16x8*)(HW + (size_t)sa * 128 + sub * 8);
        f16x8 vb = *(const f16x8*)(HW + (size_t)sb * 128 + sub * 8);
        #pragma unroll
        for (int j = 0; j < 8; j++) {
            acc0[j] = fmaf(na, (float)va[j], acc0[j]);
            acc1[j] = fmaf(nb, (float)vb[j], acc1[j]);
        }
    }
    float dn = dinv[node];
    #pragma unroll
    for (int j = 0; j < 8; j++) {
        acc0[j] += acc1[j];
        acc0[j] += __shfl_xor(acc0[j], 16, 64);
        acc0[j] += __shfl_xor(acc0[j], 32, 64);
    }
    int ch = sub * 8;
    float vfin[8];
    float s = 0.f, s2 = 0.f;
    #pragma unroll
    for (int j = 0; j < 8; j++) {
        float v = fmaf(g2[ch + j], acc0[j] * dn, b2[ch + j] + c2b[ch + j]);
        vfin[j] = v;
        s += v; s2 = fmaf(v, v, s2);
    }
    #pragma unroll
    for (int off = 1; off < 16; off <<= 1) {
        s += __shfl_xor(s, off, 64);
        s2 += __shfl_xor(s2, off, 64);
    }
    float mu = s * (1.f / 128.f);
    float rr = rsqrtf(s2 * (1.f / 128.f) - mu * mu + LN_EPS);
    if (q == 0) {
        float4 o0 = { (vfin[0] - mu) * rr, (vfin[1] - mu) * rr,
                      (vfin[2] - mu) * rr, (vfin[3] - mu) * rr };
        float4 o1 = { (vfin[4] - mu) * rr, (vfin[5] - mu) * rr,
                      (vfin[6] - mu) * rr, (vfin[7] - mu) * rr };
        float* dst = out + (size_t)node * 128 + ch;
        *(float4*)dst = o0;
        *(float4*)(dst + 4) = o1;
    }
}

// ---------------- host launch ----------------

extern "C" void kernel_launch(void* const* d_in, const int* in_sizes, int n_in,
                              void* d_out, int out_size, void* d_ws, size_t ws_size,
                              hipStream_t stream) {
    const float* x    = (const float*)d_in[0];
    const int*   ei   = (const int*)d_in[1];
    const float* c1w  = (const float*)d_in[2];
    const float* c1b  = (const float*)d_in[3];
    const float* c2w  = (const float*)d_in[4];
    const float* c2b  = (const float*)d_in[5];
    const float* sigw = (const float*)d_in[6];
    const float* sigb = (const float*)d_in[7];
    const float* f1w  = (const float*)d_in[8];
    const float* f1b  = (const float*)d_in[9];
    const float* f2w  = (const float*)d_in[10];
    const float* f2b  = (const float*)d_in[11];
    const float* f3w  = (const float*)d_in[12];
    const float* f3b  = (const float*)d_in[13];
    const float* f4w  = (const float*)d_in[14];
    const float* f4b  = (const float*)d_in[15];
    float* out = (float*)d_out;

    int nN = in_sizes[0] / IN_CH;      // 50000
    int nE = in_sizes[1] / 2;          // 800000
    int nT = nE + nN;                  // 850000

    char* base = (char*)d_ws;
    size_t off = 0;
    auto alloc = [&](size_t bytes) { size_t o = off; off += (bytes + 255) & ~(size_t)255; return o; };

    size_t o_spart  = alloc((size_t)NSLOT * 256 * 4);
    size_t o_ctr    = alloc(256);
    size_t zero_bytes = off;                   // zero sig_part/ctr only
    size_t o_histc  = alloc((size_t)NC * nN * 4);
    size_t o_cbase  = alloc((size_t)NC * nN * 4);
    size_t o_g1     = alloc(256 * 4);
    size_t o_b1     = alloc(256 * 4);
    size_t o_g2     = alloc(128 * 4);
    size_t o_b2     = alloc(128 * 4);
    size_t o_rowst  = alloc((size_t)nN * 4);
    size_t o_cntt   = alloc((size_t)nN * 4);
    size_t o_dinv   = alloc((size_t)nN * 4);
    size_t o_src    = alloc((size_t)nT * 2);
    size_t o_wt1    = alloc(512 * 256 * 2);
    size_t o_wt2    = alloc(128 * 256 * 2);
    size_t o_xh     = alloc((size_t)nN * 256 * 2);
    size_t o_AX     = alloc((size_t)nN * 256 * 2);
    size_t o_HW     = alloc((size_t)nN * 128 * 2);

    float* spart  = (float*)(base + o_spart);
    int*   ctr    = (int*)(base + o_ctr);
    int*   histc  = (int*)(base + o_histc);
    int*   cbase  = (int*)(base + o_cbase);
    float* g1     = (float*)(base + o_g1);
    float* b1     = (float*)(base + o_b1);
    float* g2     = (float*)(base + o_g2);
    float* b2     = (float*)(base + o_b2);
    int*   rowst  = (int*)(base + o_rowst);
    int*   cntt   = (int*)(base + o_cntt);
    float* dinv   = (float*)(base + o_dinv);
    u16*   srcs   = (u16*)(base + o_src);
    f16*   Wt1    = (f16*)(base + o_wt1);
    f16*   Wt2    = (f16*)(base + o_wt2);
    f16*   xh     = (f16*)(base + o_xh);
    f16*   AX     = (f16*)(base + o_AX);
    f16*   HW     = (f16*)(base + o_HW);

    hipMemsetAsync(base, 0, zero_bytes, stream);

    int nPrep = (512 * 256 + 128 * 256) / 256;         // 640
    k_hist<<<NR * NC + nPrep, 256, 0, stream>>>(ei, nE, nN, histc, sigw, c1w, c2w, Wt1, Wt2);
    k_alloc<<<(nN + 255) / 256, 256, 0, stream>>>(histc, rowst, cbase, cntt, dinv, ctr, nN);

    int nCast = (nN * IN_CH + 2047) / 2048;            // 6250
    k_fillcast<<<NR * NC + nCast, 256, 0, stream>>>(ei, nE, nN, cbase, srcs, x, xh, dinv, nCast);

    int nb4 = (nN + 3) / 4;
    int mg = (nN + 31) / 32;
    k_aggX<<<nb4, 256, 0, stream>>>(xh, rowst, cntt, srcs, dinv, AX, nN);
    k_gemm_sig<<<mg, 256, 0, stream>>>(AX, Wt1, sigb, spart, nN);
    k_fc<<<1, 256, 0, stream>>>(spart, f1w, f1b, f2w, f2b, f3w, f3b, f4w, f4b, g1, b1, g2, b2);
    k_c1f<<<mg, 256, 0, stream>>>(AX, Wt1 + 256 * 256, Wt2, g1, b1, c1b, dinv, HW, nN);
    k_agg2<<<nb4, 256, 0, stream>>>(HW, rowst, cntt, srcs, dinv, g2, b2, c2b, out, nN);
}